// Round 6
// baseline (20.552 us; speedup 1.0000x reference)
//
#include <hip/hip_runtime.h>
#include <hip/hip_bf16.h>

// Shapes (fixed by the reference)
constexpr int IN_F  = 1024;
constexpr int OUT_F = 1024;
constexpr int LAT   = 16;
constexpr int BATCH = 256;

typedef __attribute__((ext_vector_type(8))) short  bf16x8;  // 8 bf16 (4 VGPRs)
typedef __attribute__((ext_vector_type(4))) float  f32x4;   // MFMA accumulator

static __device__ __forceinline__ unsigned short bf16_bits(float v) {
  __hip_bfloat16 h = __float2bfloat16(v);
  return *reinterpret_cast<unsigned short*>(&h);
}
static __device__ __forceinline__ float bf16_f32(unsigned short u) {
  __hip_bfloat16 h;
  *reinterpret_cast<unsigned short*>(&h) = u;
  return __bfloat162float(h);
}

// ---------------------------------------------------------------------------
// Single kernel, no grid sync. Block bid -> tile n0=(bid&31)*32, m0=(bid>>5)*32.
//
// Phase A: s[32 rows][1024 i] = z @ lt_w^T + lt_b via MFMA, swapped operands:
//   D[i][batch] = (lt_w tile) x (z^T), so each lane holds 4 CONSECUTIVE i for
//   one batch row -> packed ds_write_b64 into XOR-swizzled s_lds[row][i].
//   K=16 padded to 32 as hi/lo split: MFMA1 [w_hi|w_hi]x[z_hi|z_lo],
//   MFMA2 [w_lo|0]x[z_hi|z_lo]  => ~f32-exact.
//
// Phase B: double-GEMM K-loop. A-fragments (xs=bf16(x*s), ss=bf16(s*s)) are
//   built IN REGISTERS from global x (row-major, k-contiguous = frag layout)
//   and s_lds reads; only W/W^2 tiles go through (double-buffered) LDS with
//   in-register transpose+square staging. acc1=xs@W, acc2=ss@W^2;
//   out = acc1*rsqrt(acc2+1e-8)+bias.
//
// 256 blocks (1/CU), 256 threads (4 waves, 2x2 of 16x16 MFMA). LDS 80KB.
// ---------------------------------------------------------------------------
__global__ __launch_bounds__(256) void fused_mod(
    const float* __restrict__ tensor, const float* __restrict__ z,
    const float* __restrict__ lt_w, const float* __restrict__ lt_b,
    const float* __restrict__ W, const float* __restrict__ bias,
    float* __restrict__ out) {
  __shared__ __hip_bfloat16 s_lds[32 * 1024];      // 64KB: s rows (swizzled)
  __shared__ __hip_bfloat16 wtile[2][2][32 * 64];  // 16KB: dbuf wt, w2t

  const int bid = blockIdx.x;
  const int t = threadIdx.x;
  const int n0 = (bid & 31) * 32;
  const int m0 = (bid >> 5) * 32;
  const int lane = t & 63;
  const int wave = t >> 6;
  const int lm = lane & 15;
  const int h = lane >> 4;     // 0..3

  // ---- W staging map: thread t -> column n_l = t&31, k-octet kr = t>>5 ----
  const int wn_l = t & 31;
  const int wkr = t >> 5;
  const int wswz = wn_l * 128 + ((wkr ^ (wn_l & 7)) << 4);
  const int wg_base = (wkr * 8) * OUT_F + n0 + wn_l;

  // ---- Phase B fragment addressing ----
  const int wm = wave >> 1;
  const int wn = wave & 1;
  const int arow = wm * 16 + lm;   // batch row (local)
  const int brow = wn * 16 + lm;   // W col (local)
  const int boff0 = brow * 128 + (((0 + h) ^ (brow & 7)) << 4);
  const int boff1 = brow * 128 + (((4 + h) ^ (brow & 7)) << 4);
  char* const sl = reinterpret_cast<char*>(s_lds) + arow * 2048;
  const int sxor = (arow & 7) << 4;
  const float* const xrow = tensor + (m0 + arow) * IN_F + h * 8;

  // ---- prologue global loads for K-iter 0 (overlap with phase A) ----
  float wv[8];
#pragma unroll
  for (int j = 0; j < 8; ++j) wv[j] = W[wg_base + j * OUT_F];
  float4 x0 = *reinterpret_cast<const float4*>(xrow);
  float4 x1 = *reinterpret_cast<const float4*>(xrow + 4);
  float4 x2 = *reinterpret_cast<const float4*>(xrow + 32);
  float4 x3 = *reinterpret_cast<const float4*>(xrow + 36);

  // ================= Phase A: s via MFMA (swapped operands) =================
  {
    const int koct = h & 1;
    // B-frags: z for the two batch halves, [z_hi | z_lo] split
    bf16x8 zfrag[2];
#pragma unroll
    for (int bh = 0; bh < 2; ++bh) {
      const float* zp = z + (m0 + bh * 16 + lm) * LAT + koct * 8;
      float4 v0 = *reinterpret_cast<const float4*>(zp);
      float4 v1 = *reinterpret_cast<const float4*>(zp + 4);
      float v[8] = {v0.x, v0.y, v0.z, v0.w, v1.x, v1.y, v1.z, v1.w};
      union { unsigned short u[8]; bf16x8 b; } fz;
#pragma unroll
      for (int j = 0; j < 8; ++j) {
        unsigned short hi = bf16_bits(v[j]);
        fz.u[j] = (h < 2) ? hi : bf16_bits(v[j] - bf16_f32(hi));
      }
      zfrag[bh] = fz.b;
    }
    // 16 i-tiles per wave; A = lt_w fragment (row = i-local = lm)
    for (int itl = 0; itl < 16; ++itl) {
      const int i0 = (wave * 16 + itl) * 16;
      const float* wp = lt_w + (i0 + lm) * LAT + koct * 8;
      float4 v0 = *reinterpret_cast<const float4*>(wp);
      float4 v1 = *reinterpret_cast<const float4*>(wp + 4);
      float v[8] = {v0.x, v0.y, v0.z, v0.w, v1.x, v1.y, v1.z, v1.w};
      union { unsigned short u[8]; bf16x8 b; } f1, f2;
#pragma unroll
      for (int j = 0; j < 8; ++j) {
        unsigned short hi = bf16_bits(v[j]);
        f1.u[j] = hi;                                           // [w_hi|w_hi]
        f2.u[j] = (h < 2) ? bf16_bits(v[j] - bf16_f32(hi)) : 0; // [w_lo|0]
      }
      const float4 bq = *reinterpret_cast<const float4*>(lt_b + i0 + h * 4);
      const int cbase = (i0 >> 3) + (h >> 1);  // 16B chunk index of i0+h*4
      const int sub8 = (h & 1) * 8;            // byte offset within chunk
#pragma unroll
      for (int bh = 0; bh < 2; ++bh) {
        f32x4 sacc = {0.f, 0.f, 0.f, 0.f};
        sacc = __builtin_amdgcn_mfma_f32_16x16x32_bf16(f1.b, zfrag[bh], sacc, 0, 0, 0);
        sacc = __builtin_amdgcn_mfma_f32_16x16x32_bf16(f2.b, zfrag[bh], sacc, 0, 0, 0);
        const int r = bh * 16 + lm;  // batch row (local)
        union { unsigned short u[4]; uint2 d; } pk;
        pk.u[0] = bf16_bits(sacc[0] + bq.x);
        pk.u[1] = bf16_bits(sacc[1] + bq.y);
        pk.u[2] = bf16_bits(sacc[2] + bq.z);
        pk.u[3] = bf16_bits(sacc[3] + bq.w);
        const int off = r * 2048 + ((cbase ^ (r & 7)) << 4) + sub8;
        *reinterpret_cast<uint2*>(reinterpret_cast<char*>(s_lds) + off) = pk.d;
      }
    }
  }
  __syncthreads();  // s_lds ready; read-only below

  // ================= Phase B: double-GEMM K-loop =================
  f32x4 acc1 = {0.f, 0.f, 0.f, 0.f};
  f32x4 acc2 = {0.f, 0.f, 0.f, 0.f};

  // first s fragments (chunks h and 4+h of tstep 0)
  bf16x8 s8a = *reinterpret_cast<const bf16x8*>(sl + (((0 + h) ^ (arow & 7)) << 4));
  bf16x8 s8b = *reinterpret_cast<const bf16x8*>(sl + (((4 + h) ^ (arow & 7)) << 4));

#pragma unroll
  for (int tstep = 0; tstep < IN_F / 64; ++tstep) {
    char* l2 = reinterpret_cast<char*>(wtile[tstep & 1][0]);
    char* l3 = reinterpret_cast<char*>(wtile[tstep & 1][1]);
    // stage W tiles (bf16 + squared bf16) from wv regs
    union { unsigned short u[8]; bf16x8 b; } pw, pw2;
#pragma unroll
    for (int j = 0; j < 8; ++j) {
      pw.u[j]  = bf16_bits(wv[j]);
      pw2.u[j] = bf16_bits(wv[j] * wv[j]);
    }
    *reinterpret_cast<bf16x8*>(l2 + wswz) = pw.b;
    *reinterpret_cast<bf16x8*>(l3 + wswz) = pw2.b;
    __syncthreads();
    // B-fragment reads (current buffer)
    bf16x8 b1_0 = *reinterpret_cast<const bf16x8*>(l2 + boff0);
    bf16x8 b2_0 = *reinterpret_cast<const bf16x8*>(l3 + boff0);
    bf16x8 b1_1 = *reinterpret_cast<const bf16x8*>(l2 + boff1);
    bf16x8 b2_1 = *reinterpret_cast<const bf16x8*>(l3 + boff1);
    // build A-fragments in registers: xs = bf16(x*s), ss = bf16(s*s)
    union { unsigned short u[8]; bf16x8 b; } fxs0, fss0, fxs1, fss1;
    {
      const float xv0[8] = {x0.x, x0.y, x0.z, x0.w, x1.x, x1.y, x1.z, x1.w};
      const float xv1[8] = {x2.x, x2.y, x2.z, x2.w, x3.x, x3.y, x3.z, x3.w};
#pragma unroll
      for (int j = 0; j < 8; ++j) {
        const float sa = bf16_f32((unsigned short)s8a[j]);
        const float sb = bf16_f32((unsigned short)s8b[j]);
        fxs0.u[j] = bf16_bits(xv0[j] * sa);
        fss0.u[j] = bf16_bits(sa * sa);
        fxs1.u[j] = bf16_bits(xv1[j] * sb);
        fss1.u[j] = bf16_bits(sb * sb);
      }
    }
    // prefetch next K-tile inputs (hidden under MFMA + next staging)
    if (tstep < IN_F / 64 - 1) {
      const int k0 = (tstep + 1) * 64;
#pragma unroll
      for (int j = 0; j < 8; ++j) wv[j] = W[k0 * OUT_F + wg_base + j * OUT_F];
      x0 = *reinterpret_cast<const float4*>(xrow + k0);
      x1 = *reinterpret_cast<const float4*>(xrow + k0 + 4);
      x2 = *reinterpret_cast<const float4*>(xrow + k0 + 32);
      x3 = *reinterpret_cast<const float4*>(xrow + k0 + 36);
      const int c0 = (tstep + 1) * 8 + h;
      s8a = *reinterpret_cast<const bf16x8*>(sl + ((c0 ^ (arow & 7)) << 4));
      s8b = *reinterpret_cast<const bf16x8*>(sl + (((c0 + 4) ^ (arow & 7)) << 4));
    }
    // MFMA (two K=32 sub-steps)
    acc1 = __builtin_amdgcn_mfma_f32_16x16x32_bf16(fxs0.b, b1_0, acc1, 0, 0, 0);
    acc2 = __builtin_amdgcn_mfma_f32_16x16x32_bf16(fss0.b, b2_0, acc2, 0, 0, 0);
    acc1 = __builtin_amdgcn_mfma_f32_16x16x32_bf16(fxs1.b, b1_1, acc1, 0, 0, 0);
    acc2 = __builtin_amdgcn_mfma_f32_16x16x32_bf16(fss1.b, b2_1, acc2, 0, 0, 0);
  }

  // epilogue: C/D layout col = lane&15, row = (lane>>4)*4 + reg
  const int col = n0 + wn * 16 + lm;
  const float bs = bias[col];
#pragma unroll
  for (int q = 0; q < 4; ++q) {
    const int row = m0 + wm * 16 + h * 4 + q;
    out[row * OUT_F + col] = acc1[q] * __frsqrt_rn(acc2[q] + 1e-8f) + bs;
  }
}

// ---------------------------------------------------------------------------
extern "C" void kernel_launch(void* const* d_in, const int* in_sizes, int n_in,
                              void* d_out, int out_size, void* d_ws, size_t ws_size,
                              hipStream_t stream) {
  const float* tensor = (const float*)d_in[0];  // [256][1024]
  const float* z      = (const float*)d_in[1];  // [256][16]
  const float* W      = (const float*)d_in[2];  // [1024][1024]
  const float* bias   = (const float*)d_in[3];  // [1024]
  const float* lt_w   = (const float*)d_in[4];  // [1024][16]
  const float* lt_b   = (const float*)d_in[5];  // [1024]
  float* out = (float*)d_out;

  fused_mod<<<256, 256, 0, stream>>>(tensor, z, lt_w, lt_b, W, bias, out);
}

// Round 7
// 17.254 us; speedup vs baseline: 1.1912x; 1.1912x over previous
//
#include <hip/hip_runtime.h>
#include <hip/hip_bf16.h>

// Shapes (fixed by the reference)
constexpr int IN_F  = 1024;
constexpr int OUT_F = 1024;
constexpr int LAT   = 16;
constexpr int BATCH = 256;

typedef __attribute__((ext_vector_type(8))) short  bf16x8;  // 8 bf16 (4 VGPRs)
typedef __attribute__((ext_vector_type(4))) float  f32x4;   // MFMA accumulator

static __device__ __forceinline__ unsigned short bf16_bits(float v) {
  __hip_bfloat16 h = __float2bfloat16(v);
  return *reinterpret_cast<unsigned short*>(&h);
}
static __device__ __forceinline__ float bf16_f32(unsigned short u) {
  __hip_bfloat16 h;
  *reinterpret_cast<unsigned short*>(&h) = u;
  return __bfloat162float(h);
}

// ---------------------------------------------------------------------------
// Single kernel, no grid sync. Block bid -> tile n0=(bid&31)*32, m0=(bid>>5)*32.
//
// Phase A (R6-proven): s[32][1024] = z @ lt_w^T + lt_b via swapped-operand
//   MFMA (D[i][batch]), packed uint2 ds_writes into XOR-swizzled s_lds.
//   K=16 padded to 32 as hi/lo split => ~f32-exact. itl loop unrolled x4 so
//   4 lt_w tile loads are in flight (phase A is latency-bound at 1 wave/SIMD).
//
// Phase B (R5-proven, 18.9us): double-buffered K-loop; staging threads build
//   xs=bf16(x*s), ss=bf16(s*s) (once per element, from x regs + s_lds) and
//   wt/w2t (in-register W transpose+square); 4 MFMAs/iter on swizzled tiles;
//   out = acc1*rsqrt(acc2+1e-8)+bias.
//
// 256 blocks (1/CU), 256 threads (4 waves, 2x2 of 16x16 MFMA). LDS 96KB.
// ---------------------------------------------------------------------------
__global__ __launch_bounds__(256) void fused_mod(
    const float* __restrict__ tensor, const float* __restrict__ z,
    const float* __restrict__ lt_w, const float* __restrict__ lt_b,
    const float* __restrict__ W, const float* __restrict__ bias,
    float* __restrict__ out) {
  __shared__ __hip_bfloat16 s_lds[32 * 1024];      // 64KB: s rows (swizzled)
  __shared__ __hip_bfloat16 tiles[2][4][32 * 64];  // 32KB: dbuf xs,ss,wt,w2t

  const int bid = blockIdx.x;
  const int t = threadIdx.x;
  const int n0 = (bid & 31) * 32;
  const int m0 = (bid >> 5) * 32;
  const int lane = t & 63;
  const int wave = t >> 6;
  const int lm = lane & 15;
  const int h = lane >> 4;     // 0..3

  // ---- staging maps (phase B) ----
  const int srow = t >> 3;          // 0..31
  const int sc = t & 7;             // 0..7
  const int swz_off = srow * 128 + ((sc ^ (srow & 7)) << 4);
  const int xg = (m0 + srow) * IN_F + sc * 8;
  const int wn_l = t & 31;
  const int wkr = t >> 5;
  const int wswz = wn_l * 128 + ((wkr ^ (wn_l & 7)) << 4);
  const int wg_base = (wkr * 8) * OUT_F + n0 + wn_l;

  // ---- prologue global loads for K-iter 0 (overlap with phase A) ----
  float4 xa = *reinterpret_cast<const float4*>(tensor + xg);
  float4 xb = *reinterpret_cast<const float4*>(tensor + xg + 4);
  float wv[8];
#pragma unroll
  for (int j = 0; j < 8; ++j) wv[j] = W[wg_base + j * OUT_F];

  // ================= Phase A: s via MFMA (swapped operands) =================
  {
    const int koct = h & 1;
    // B-frags: z for the two batch halves, [z_hi | z_lo] split
    bf16x8 zfrag[2];
#pragma unroll
    for (int bh = 0; bh < 2; ++bh) {
      const float* zp = z + (m0 + bh * 16 + lm) * LAT + koct * 8;
      float4 v0 = *reinterpret_cast<const float4*>(zp);
      float4 v1 = *reinterpret_cast<const float4*>(zp + 4);
      float v[8] = {v0.x, v0.y, v0.z, v0.w, v1.x, v1.y, v1.z, v1.w};
      union { unsigned short u[8]; bf16x8 b; } fz;
#pragma unroll
      for (int j = 0; j < 8; ++j) {
        unsigned short hi = bf16_bits(v[j]);
        fz.u[j] = (h < 2) ? hi : bf16_bits(v[j] - bf16_f32(hi));
      }
      zfrag[bh] = fz.b;
    }
    // 16 i-tiles per wave; A = lt_w fragment (row = i-local = lm)
#pragma unroll 4
    for (int itl = 0; itl < 16; ++itl) {
      const int i0 = (wave * 16 + itl) * 16;
      const float* wp = lt_w + (i0 + lm) * LAT + koct * 8;
      float4 v0 = *reinterpret_cast<const float4*>(wp);
      float4 v1 = *reinterpret_cast<const float4*>(wp + 4);
      float v[8] = {v0.x, v0.y, v0.z, v0.w, v1.x, v1.y, v1.z, v1.w};
      union { unsigned short u[8]; bf16x8 b; } f1, f2;
#pragma unroll
      for (int j = 0; j < 8; ++j) {
        unsigned short hi = bf16_bits(v[j]);
        f1.u[j] = hi;                                           // [w_hi|w_hi]
        f2.u[j] = (h < 2) ? bf16_bits(v[j] - bf16_f32(hi)) : 0; // [w_lo|0]
      }
      const float4 bq = *reinterpret_cast<const float4*>(lt_b + i0 + h * 4);
      const int cbase = (i0 >> 3) + (h >> 1);  // 16B chunk index of i0+h*4
      const int sub8 = (h & 1) * 8;            // byte offset within chunk
#pragma unroll
      for (int bh = 0; bh < 2; ++bh) {
        f32x4 sacc = {0.f, 0.f, 0.f, 0.f};
        sacc = __builtin_amdgcn_mfma_f32_16x16x32_bf16(f1.b, zfrag[bh], sacc, 0, 0, 0);
        sacc = __builtin_amdgcn_mfma_f32_16x16x32_bf16(f2.b, zfrag[bh], sacc, 0, 0, 0);
        const int r = bh * 16 + lm;  // batch row (local)
        union { unsigned short u[4]; uint2 d; } pk;
        pk.u[0] = bf16_bits(sacc[0] + bq.x);
        pk.u[1] = bf16_bits(sacc[1] + bq.y);
        pk.u[2] = bf16_bits(sacc[2] + bq.z);
        pk.u[3] = bf16_bits(sacc[3] + bq.w);
        const int off = r * 2048 + ((cbase ^ (r & 7)) << 4) + sub8;
        *reinterpret_cast<uint2*>(reinterpret_cast<char*>(s_lds) + off) = pk.d;
      }
    }
  }
  __syncthreads();  // s_lds ready (read-only from here on)

  // ================= Phase B: double-GEMM K-loop (R5-proven) ===============
  const int wm = wave >> 1;
  const int wn = wave & 1;
  const int arow = wm * 16 + lm;
  const int brow = wn * 16 + lm;
  const int aoff0 = arow * 128 + (((0 + h) ^ (arow & 7)) << 4);
  const int aoff1 = arow * 128 + (((4 + h) ^ (arow & 7)) << 4);
  const int boff0 = brow * 128 + (((0 + h) ^ (brow & 7)) << 4);
  const int boff1 = brow * 128 + (((4 + h) ^ (brow & 7)) << 4);

  f32x4 acc1 = {0.f, 0.f, 0.f, 0.f};
  f32x4 acc2 = {0.f, 0.f, 0.f, 0.f};

  // first s fragment (chunk sc of tstep 0), staging layout
  bf16x8 s8 = *reinterpret_cast<const bf16x8*>(
      reinterpret_cast<char*>(s_lds) + srow * 2048 + ((sc ^ (srow & 7)) << 4));

#pragma unroll
  for (int tstep = 0; tstep < IN_F / 64; ++tstep) {
    char* l0 = reinterpret_cast<char*>(tiles[tstep & 1][0]);
    char* l1 = reinterpret_cast<char*>(tiles[tstep & 1][1]);
    char* l2 = reinterpret_cast<char*>(tiles[tstep & 1][2]);
    char* l3 = reinterpret_cast<char*>(tiles[tstep & 1][3]);
    // build xs/ss from x (regs) and s (LDS frag), W tiles from wv regs
    union { unsigned short u[8]; bf16x8 b; } pxs, pss, pw, pw2;
    const float xv[8] = {xa.x, xa.y, xa.z, xa.w, xb.x, xb.y, xb.z, xb.w};
#pragma unroll
    for (int j = 0; j < 8; ++j) {
      const float sf = bf16_f32((unsigned short)s8[j]);
      pxs.u[j] = bf16_bits(xv[j] * sf);
      pss.u[j] = bf16_bits(sf * sf);
      pw.u[j]  = bf16_bits(wv[j]);
      pw2.u[j] = bf16_bits(wv[j] * wv[j]);
    }
    *reinterpret_cast<bf16x8*>(l0 + swz_off) = pxs.b;
    *reinterpret_cast<bf16x8*>(l1 + swz_off) = pss.b;
    *reinterpret_cast<bf16x8*>(l2 + wswz) = pw.b;
    *reinterpret_cast<bf16x8*>(l3 + wswz) = pw2.b;
    __syncthreads();
    // prefetch next K-tile inputs (hidden under ds_read + MFMA below)
    if (tstep < IN_F / 64 - 1) {
      const int k0 = (tstep + 1) * 64;
      xa = *reinterpret_cast<const float4*>(tensor + xg + k0);
      xb = *reinterpret_cast<const float4*>(tensor + xg + k0 + 4);
      const int cs = (tstep + 1) * 8 + sc;
      s8 = *reinterpret_cast<const bf16x8*>(
          reinterpret_cast<char*>(s_lds) + srow * 2048 + ((cs ^ (srow & 7)) << 4));
#pragma unroll
      for (int j = 0; j < 8; ++j) wv[j] = W[k0 * OUT_F + wg_base + j * OUT_F];
    }
    // MFMA on current buffer (two K=32 sub-steps) — proven section
    bf16x8 a1 = *reinterpret_cast<const bf16x8*>(l0 + aoff0);
    bf16x8 a2 = *reinterpret_cast<const bf16x8*>(l1 + aoff0);
    bf16x8 b1 = *reinterpret_cast<const bf16x8*>(l2 + boff0);
    bf16x8 b2 = *reinterpret_cast<const bf16x8*>(l3 + boff0);
    acc1 = __builtin_amdgcn_mfma_f32_16x16x32_bf16(a1, b1, acc1, 0, 0, 0);
    acc2 = __builtin_amdgcn_mfma_f32_16x16x32_bf16(a2, b2, acc2, 0, 0, 0);
    a1 = *reinterpret_cast<const bf16x8*>(l0 + aoff1);
    a2 = *reinterpret_cast<const bf16x8*>(l1 + aoff1);
    b1 = *reinterpret_cast<const bf16x8*>(l2 + boff1);
    b2 = *reinterpret_cast<const bf16x8*>(l3 + boff1);
    acc1 = __builtin_amdgcn_mfma_f32_16x16x32_bf16(a1, b1, acc1, 0, 0, 0);
    acc2 = __builtin_amdgcn_mfma_f32_16x16x32_bf16(a2, b2, acc2, 0, 0, 0);
  }

  // epilogue: C/D layout col = lane&15, row = (lane>>4)*4 + reg
  const int col = n0 + wn * 16 + lm;
  const float bs = bias[col];
#pragma unroll
  for (int q = 0; q < 4; ++q) {
    const int row = m0 + wm * 16 + h * 4 + q;
    out[row * OUT_F + col] = acc1[q] * __frsqrt_rn(acc2[q] + 1e-8f) + bs;
  }
}

// ---------------------------------------------------------------------------
extern "C" void kernel_launch(void* const* d_in, const int* in_sizes, int n_in,
                              void* d_out, int out_size, void* d_ws, size_t ws_size,
                              hipStream_t stream) {
  const float* tensor = (const float*)d_in[0];  // [256][1024]
  const float* z      = (const float*)d_in[1];  // [256][16]
  const float* W      = (const float*)d_in[2];  // [1024][1024]
  const float* bias   = (const float*)d_in[3];  // [1024]
  const float* lt_w   = (const float*)d_in[4];  // [1024][16]
  const float* lt_b   = (const float*)d_in[5];  // [1024]
  float* out = (float*)d_out;

  fused_mod<<<256, 256, 0, stream>>>(tensor, z, lt_w, lt_b, W, bias, out);
}

// Round 8
// 15.286 us; speedup vs baseline: 1.3446x; 1.1288x over previous
//
#include <hip/hip_runtime.h>
#include <hip/hip_bf16.h>

// Shapes (fixed by the reference)
constexpr int IN_F  = 1024;
constexpr int OUT_F = 1024;
constexpr int LAT   = 16;
constexpr int BATCH = 256;

typedef __attribute__((ext_vector_type(8))) short  bf16x8;  // 8 bf16 (4 VGPRs)
typedef __attribute__((ext_vector_type(4))) float  f32x4;   // MFMA accumulator

static __device__ __forceinline__ unsigned short bf16_bits(float v) {
  __hip_bfloat16 h = __float2bfloat16(v);
  return *reinterpret_cast<unsigned short*>(&h);
}
static __device__ __forceinline__ float bf16_f32(unsigned short u) {
  __hip_bfloat16 h;
  *reinterpret_cast<unsigned short*>(&h) = u;
  return __bfloat162float(h);
}

// ---------------------------------------------------------------------------
// Single kernel. Block bid -> tile n0=(bid&31)*32, m0=(bid>>5)*32.
//
// Phase A (R7-proven): s[32][1024] = z @ lt_w^T + lt_b via swapped-operand
//   MFMA, hi/lo K=16->32 split (~f32-exact), packed uint2 writes into
//   XOR-swizzled s_lds. One __syncthreads after.
//
// Phase B (NEW: split-K, barrier-free): wave w owns K in [256w, 256w+256)
//   and computes the WHOLE 32x32 tile as 4 partial 16x16 accumulators per
//   GEMM. Per K=64 step: wave stages its own W/W^2 slice into its PRIVATE
//   LDS double-buffer (same-wave ds_write->ds_read: no barrier needed);
//   A-fragments (xs=bf16(x*s), ss=bf16(s*s)) built in registers from global
//   x (k-contiguous float4 pairs = frag layout) and s_lds — no duplication,
//   waves own disjoint K. Zero __syncthreads in the K-loop.
//   LDS ops: 80 b128/lane total (vs 208 in R7); barriers 16 -> 0.
//
// Combine: one barrier; wave w sums the 4 waves' partials for its (mi,ni)
//   quadrant from LDS, applies rsqrt demod + bias, stores.
//
// 256 blocks (1/CU), 256 threads (4 waves). LDS 128KB.
// ---------------------------------------------------------------------------
__global__ __launch_bounds__(256) void fused_mod(
    const float* __restrict__ tensor, const float* __restrict__ z,
    const float* __restrict__ lt_w, const float* __restrict__ lt_b,
    const float* __restrict__ W, const float* __restrict__ bias,
    float* __restrict__ out) {
  __shared__ __hip_bfloat16 s_lds[32 * 1024];         // 64KB: s rows (swizzled)
  __shared__ __hip_bfloat16 wbuf[4][2][2][32 * 64];   // 64KB: per-wave dbuf wt/w2t

  const int bid = blockIdx.x;
  const int t = threadIdx.x;
  const int n0 = (bid & 31) * 32;
  const int m0 = (bid >> 5) * 32;
  const int lane = t & 63;
  const int wave = t >> 6;
  const int lm = lane & 15;
  const int h = lane >> 4;     // 0..3

  // ================= Phase A: s via MFMA (swapped operands) =================
  {
    const int koct = h & 1;
    // B-frags: z for the two batch halves, [z_hi | z_lo] split
    bf16x8 zfrag[2];
#pragma unroll
    for (int bh = 0; bh < 2; ++bh) {
      const float* zp = z + (m0 + bh * 16 + lm) * LAT + koct * 8;
      float4 v0 = *reinterpret_cast<const float4*>(zp);
      float4 v1 = *reinterpret_cast<const float4*>(zp + 4);
      float v[8] = {v0.x, v0.y, v0.z, v0.w, v1.x, v1.y, v1.z, v1.w};
      union { unsigned short u[8]; bf16x8 b; } fz;
#pragma unroll
      for (int j = 0; j < 8; ++j) {
        unsigned short hi = bf16_bits(v[j]);
        fz.u[j] = (h < 2) ? hi : bf16_bits(v[j] - bf16_f32(hi));
      }
      zfrag[bh] = fz.b;
    }
    // 16 i-tiles per wave; A = lt_w fragment (row = i-local = lm)
#pragma unroll 4
    for (int itl = 0; itl < 16; ++itl) {
      const int i0 = (wave * 16 + itl) * 16;
      const float* wp = lt_w + (i0 + lm) * LAT + koct * 8;
      float4 v0 = *reinterpret_cast<const float4*>(wp);
      float4 v1 = *reinterpret_cast<const float4*>(wp + 4);
      float v[8] = {v0.x, v0.y, v0.z, v0.w, v1.x, v1.y, v1.z, v1.w};
      union { unsigned short u[8]; bf16x8 b; } f1, f2;
#pragma unroll
      for (int j = 0; j < 8; ++j) {
        unsigned short hi = bf16_bits(v[j]);
        f1.u[j] = hi;                                           // [w_hi|w_hi]
        f2.u[j] = (h < 2) ? bf16_bits(v[j] - bf16_f32(hi)) : 0; // [w_lo|0]
      }
      const float4 bq = *reinterpret_cast<const float4*>(lt_b + i0 + h * 4);
      const int cbase = (i0 >> 3) + (h >> 1);  // 16B chunk index of i0+h*4
      const int sub8 = (h & 1) * 8;            // byte offset within chunk
#pragma unroll
      for (int bh = 0; bh < 2; ++bh) {
        f32x4 sacc = {0.f, 0.f, 0.f, 0.f};
        sacc = __builtin_amdgcn_mfma_f32_16x16x32_bf16(f1.b, zfrag[bh], sacc, 0, 0, 0);
        sacc = __builtin_amdgcn_mfma_f32_16x16x32_bf16(f2.b, zfrag[bh], sacc, 0, 0, 0);
        const int r = bh * 16 + lm;  // batch row (local)
        union { unsigned short u[4]; uint2 d; } pk;
        pk.u[0] = bf16_bits(sacc[0] + bq.x);
        pk.u[1] = bf16_bits(sacc[1] + bq.y);
        pk.u[2] = bf16_bits(sacc[2] + bq.z);
        pk.u[3] = bf16_bits(sacc[3] + bq.w);
        const int off = r * 2048 + ((cbase ^ (r & 7)) << 4) + sub8;
        *reinterpret_cast<uint2*>(reinterpret_cast<char*>(s_lds) + off) = pk.d;
      }
    }
  }
  __syncthreads();  // s_lds ready (read-only from here on)

  // ================= Phase B: split-K, barrier-free =================
  const int sn  = lane & 31;   // W staging: column n-local
  const int shb = lane >> 5;   // 0/1: k-octet parity

  f32x4 acc1[2][2], acc2[2][2];
#pragma unroll
  for (int mi = 0; mi < 2; ++mi)
#pragma unroll
    for (int ni = 0; ni < 2; ++ni) {
      acc1[mi][ni] = (f32x4){0.f, 0.f, 0.f, 0.f};
      acc2[mi][ni] = (f32x4){0.f, 0.f, 0.f, 0.f};
    }

#pragma unroll
  for (int tt = 0; tt < 4; ++tt) {
    const int k0 = (wave * 4 + tt) * 64;
    char* wt = reinterpret_cast<char*>(&wbuf[wave][tt & 1][0][0]);
    char* w2 = reinterpret_cast<char*>(&wbuf[wave][tt & 1][1][0]);
    // ---- stage this wave's W slice (no barrier: same-wave write->read) ----
#pragma unroll
    for (int q = 0; q < 4; ++q) {
      const int koct = shb + 2 * q;  // 0..7
      union { unsigned short u[8]; bf16x8 b; } pw, pw2;
#pragma unroll
      for (int j = 0; j < 8; ++j) {
        const float v = W[(k0 + koct * 8 + j) * OUT_F + n0 + sn];
        pw.u[j]  = bf16_bits(v);
        pw2.u[j] = bf16_bits(v * v);
      }
      const int woff = sn * 128 + ((koct ^ (sn & 7)) << 4);
      *reinterpret_cast<bf16x8*>(wt + woff) = pw.b;
      *reinterpret_cast<bf16x8*>(w2 + woff) = pw2.b;
    }
    // ---- two K=32 substeps ----
#pragma unroll
    for (int sub = 0; sub < 2; ++sub) {
      const int kk = k0 + sub * 32 + h * 8;   // this lane's 8-k base
      const int c = kk >> 3;                  // s_lds chunk index
      // A-frags in registers: xs = bf16(x*s), ss = bf16(s*s); mi = 0,1
      union { unsigned short u[8]; bf16x8 b; } fxs0, fss0, fxs1, fss1;
      {
        const int r0 = lm;
        const float* xp0 = tensor + (m0 + r0) * IN_F + kk;
        float4 xa0 = *reinterpret_cast<const float4*>(xp0);
        float4 xb0 = *reinterpret_cast<const float4*>(xp0 + 4);
        bf16x8 s80 = *reinterpret_cast<const bf16x8*>(
            reinterpret_cast<char*>(s_lds) + r0 * 2048 + ((c ^ (r0 & 7)) << 4));
        const float xv0[8] = {xa0.x, xa0.y, xa0.z, xa0.w, xb0.x, xb0.y, xb0.z, xb0.w};
#pragma unroll
        for (int j = 0; j < 8; ++j) {
          const float sf = bf16_f32((unsigned short)s80[j]);
          fxs0.u[j] = bf16_bits(xv0[j] * sf);
          fss0.u[j] = bf16_bits(sf * sf);
        }
        const int r1 = 16 + lm;
        const float* xp1 = tensor + (m0 + r1) * IN_F + kk;
        float4 xa1 = *reinterpret_cast<const float4*>(xp1);
        float4 xb1 = *reinterpret_cast<const float4*>(xp1 + 4);
        bf16x8 s81 = *reinterpret_cast<const bf16x8*>(
            reinterpret_cast<char*>(s_lds) + r1 * 2048 + ((c ^ (r1 & 7)) << 4));
        const float xv1[8] = {xa1.x, xa1.y, xa1.z, xa1.w, xb1.x, xb1.y, xb1.z, xb1.w};
#pragma unroll
        for (int j = 0; j < 8; ++j) {
          const float sf = bf16_f32((unsigned short)s81[j]);
          fxs1.u[j] = bf16_bits(xv1[j] * sf);
          fss1.u[j] = bf16_bits(sf * sf);
        }
      }
      // B-frags + MFMA
#pragma unroll
      for (int ni = 0; ni < 2; ++ni) {
        const int br = ni * 16 + lm;
        const int boff = br * 128 + (((sub * 4 + h) ^ (br & 7)) << 4);
        bf16x8 b1 = *reinterpret_cast<const bf16x8*>(wt + boff);
        bf16x8 b2 = *reinterpret_cast<const bf16x8*>(w2 + boff);
        acc1[0][ni] = __builtin_amdgcn_mfma_f32_16x16x32_bf16(fxs0.b, b1, acc1[0][ni], 0, 0, 0);
        acc2[0][ni] = __builtin_amdgcn_mfma_f32_16x16x32_bf16(fss0.b, b2, acc2[0][ni], 0, 0, 0);
        acc1[1][ni] = __builtin_amdgcn_mfma_f32_16x16x32_bf16(fxs1.b, b1, acc1[1][ni], 0, 0, 0);
        acc2[1][ni] = __builtin_amdgcn_mfma_f32_16x16x32_bf16(fss1.b, b2, acc2[1][ni], 0, 0, 0);
      }
    }
  }

  // ---- write partials into this wave's wbuf region ----
  {
    float* cb = reinterpret_cast<float*>(&wbuf[wave][0][0][0]);
#pragma unroll
    for (int mi = 0; mi < 2; ++mi)
#pragma unroll
      for (int ni = 0; ni < 2; ++ni) {
        const int i1 = mi * 2 + ni;
        *reinterpret_cast<f32x4*>(cb + i1 * 256 + lane * 4) = acc1[mi][ni];
        *reinterpret_cast<f32x4*>(cb + (4 + i1) * 256 + lane * 4) = acc2[mi][ni];
      }
  }
  __syncthreads();

  // ---- combine: wave handles quadrant (mi, ni) = (wave>>1, wave&1) ----
  {
    const int mi = wave >> 1;
    const int ni = wave & 1;
    const int i1 = mi * 2 + ni;
    f32x4 t1 = {0.f, 0.f, 0.f, 0.f};
    f32x4 t2 = {0.f, 0.f, 0.f, 0.f};
#pragma unroll
    for (int v = 0; v < 4; ++v) {
      const float* src = reinterpret_cast<const float*>(&wbuf[v][0][0][0]);
      t1 += *reinterpret_cast<const f32x4*>(src + i1 * 256 + lane * 4);
      t2 += *reinterpret_cast<const f32x4*>(src + (4 + i1) * 256 + lane * 4);
    }
    const int col = n0 + ni * 16 + lm;
    const float bs = bias[col];
#pragma unroll
    for (int q = 0; q < 4; ++q) {
      const int row = m0 + mi * 16 + h * 4 + q;
      out[row * OUT_F + col] = t1[q] * __frsqrt_rn(t2[q] + 1e-8f) + bs;
    }
  }
}

// ---------------------------------------------------------------------------
extern "C" void kernel_launch(void* const* d_in, const int* in_sizes, int n_in,
                              void* d_out, int out_size, void* d_ws, size_t ws_size,
                              hipStream_t stream) {
  const float* tensor = (const float*)d_in[0];  // [256][1024]
  const float* z      = (const float*)d_in[1];  // [256][16]
  const float* W      = (const float*)d_in[2];  // [1024][1024]
  const float* bias   = (const float*)d_in[3];  // [1024]
  const float* lt_w   = (const float*)d_in[4];  // [1024][16]
  const float* lt_b   = (const float*)d_in[5];  // [1024]
  float* out = (float*)d_out;

  fused_mod<<<256, 256, 0, stream>>>(tensor, z, lt_w, lt_b, W, bias, out);
}

// Round 9
// 14.762 us; speedup vs baseline: 1.3923x; 1.0355x over previous
//
#include <hip/hip_runtime.h>
#include <hip/hip_bf16.h>

// Shapes (fixed by the reference)
constexpr int IN_F  = 1024;
constexpr int OUT_F = 1024;
constexpr int LAT   = 16;
constexpr int BATCH = 256;

typedef __attribute__((ext_vector_type(8))) short  bf16x8;  // 8 bf16 (4 VGPRs)
typedef __attribute__((ext_vector_type(4))) float  f32x4;   // MFMA accumulator

static __device__ __forceinline__ unsigned short bf16_bits(float v) {
  __hip_bfloat16 h = __float2bfloat16(v);
  return *reinterpret_cast<unsigned short*>(&h);
}
static __device__ __forceinline__ float bf16_f32(unsigned short u) {
  __hip_bfloat16 h;
  *reinterpret_cast<unsigned short*>(&h) = u;
  return __bfloat162float(h);
}

// ---------------------------------------------------------------------------
// Single kernel, 512 threads = 8 waves (2/SIMD for TLP). Block bid ->
// tile n0=(bid&31)*32, m0=(bid>>5)*32. Grid 256 blocks (1/CU, LDS 128KB).
//
// Phase A (proven): s[32][1024] = z @ lt_w^T + lt_b via swapped-operand MFMA,
//   hi/lo K=16->32 split (~f32-exact), packed uint2 writes into XOR-swizzled
//   s_lds. 8 i-tiles per wave. One __syncthreads after.
//
// Phase B (split-K, barrier-free, R8-proven + two cuts): wave w owns
//   K in [128w, 128w+128) and computes the whole 32x32 tile as 4 partial
//   16x16 accumulators per GEMM. Per K=64 step: wave stages only the W tile
//   (bf16) into its PRIVATE LDS double-buffer (same-wave write->read: no
//   barrier); the W^2 B-fragment is computed IN REGISTERS as bf16(b1^2).
//   A-fragments (xs=bf16(x*s), ss=bf16(s*s)) built in registers from global
//   x (k-contiguous float4 pairs = frag layout) and s_lds. No K-loop barriers.
//
// Combine: partials to LDS; wave w sums chunk w (w<4: acc1 quadrants,
//   w>=4: acc2 quadrants -> pass via s_lds scratch); waves 0-3 do the
//   rsqrt demod + bias epilogue.
// ---------------------------------------------------------------------------
__global__ __launch_bounds__(512) void fused_mod(
    const float* __restrict__ tensor, const float* __restrict__ z,
    const float* __restrict__ lt_w, const float* __restrict__ lt_b,
    const float* __restrict__ W, const float* __restrict__ bias,
    float* __restrict__ out) {
  __shared__ __attribute__((aligned(16))) __hip_bfloat16 s_lds[32 * 1024];   // 64KB
  __shared__ __attribute__((aligned(16))) __hip_bfloat16 wbuf[8][2][32 * 64]; // 64KB

  const int bid = blockIdx.x;
  const int t = threadIdx.x;
  const int n0 = (bid & 31) * 32;
  const int m0 = (bid >> 5) * 32;
  const int lane = t & 63;
  const int wave = t >> 6;     // 0..7
  const int lm = lane & 15;
  const int h = lane >> 4;     // 0..3

  // ================= Phase A: s via MFMA (swapped operands) =================
  {
    const int koct = h & 1;
    // B-frags: z for the two batch halves, [z_hi | z_lo] split
    bf16x8 zfrag[2];
#pragma unroll
    for (int bh = 0; bh < 2; ++bh) {
      const float* zp = z + (m0 + bh * 16 + lm) * LAT + koct * 8;
      float4 v0 = *reinterpret_cast<const float4*>(zp);
      float4 v1 = *reinterpret_cast<const float4*>(zp + 4);
      float v[8] = {v0.x, v0.y, v0.z, v0.w, v1.x, v1.y, v1.z, v1.w};
      union { unsigned short u[8]; bf16x8 b; } fz;
#pragma unroll
      for (int j = 0; j < 8; ++j) {
        unsigned short hi = bf16_bits(v[j]);
        fz.u[j] = (h < 2) ? hi : bf16_bits(v[j] - bf16_f32(hi));
      }
      zfrag[bh] = fz.b;
    }
    // 8 i-tiles per wave (64 total); A = lt_w fragment (row = i-local = lm)
#pragma unroll 4
    for (int itl = 0; itl < 8; ++itl) {
      const int i0 = (wave * 8 + itl) * 16;
      const float* wp = lt_w + (i0 + lm) * LAT + koct * 8;
      float4 v0 = *reinterpret_cast<const float4*>(wp);
      float4 v1 = *reinterpret_cast<const float4*>(wp + 4);
      float v[8] = {v0.x, v0.y, v0.z, v0.w, v1.x, v1.y, v1.z, v1.w};
      union { unsigned short u[8]; bf16x8 b; } f1, f2;
#pragma unroll
      for (int j = 0; j < 8; ++j) {
        unsigned short hi = bf16_bits(v[j]);
        f1.u[j] = hi;                                           // [w_hi|w_hi]
        f2.u[j] = (h < 2) ? bf16_bits(v[j] - bf16_f32(hi)) : 0; // [w_lo|0]
      }
      const float4 bq = *reinterpret_cast<const float4*>(lt_b + i0 + h * 4);
      const int cbase = (i0 >> 3) + (h >> 1);  // 16B chunk index of i0+h*4
      const int sub8 = (h & 1) * 8;            // byte offset within chunk
#pragma unroll
      for (int bh = 0; bh < 2; ++bh) {
        f32x4 sacc = {0.f, 0.f, 0.f, 0.f};
        sacc = __builtin_amdgcn_mfma_f32_16x16x32_bf16(f1.b, zfrag[bh], sacc, 0, 0, 0);
        sacc = __builtin_amdgcn_mfma_f32_16x16x32_bf16(f2.b, zfrag[bh], sacc, 0, 0, 0);
        const int r = bh * 16 + lm;  // batch row (local)
        union { unsigned short u[4]; uint2 d; } pk;
        pk.u[0] = bf16_bits(sacc[0] + bq.x);
        pk.u[1] = bf16_bits(sacc[1] + bq.y);
        pk.u[2] = bf16_bits(sacc[2] + bq.z);
        pk.u[3] = bf16_bits(sacc[3] + bq.w);
        const int off = r * 2048 + ((cbase ^ (r & 7)) << 4) + sub8;
        *reinterpret_cast<uint2*>(reinterpret_cast<char*>(s_lds) + off) = pk.d;
      }
    }
  }
  __syncthreads();  // s_lds ready (read-only from here on)

  // ================= Phase B: split-K (K=128/wave), barrier-free ===========
  const int sn  = lane & 31;   // W staging: column n-local
  const int shb = lane >> 5;   // 0/1: k-octet parity

  f32x4 acc1[2][2], acc2[2][2];
#pragma unroll
  for (int mi = 0; mi < 2; ++mi)
#pragma unroll
    for (int ni = 0; ni < 2; ++ni) {
      acc1[mi][ni] = (f32x4){0.f, 0.f, 0.f, 0.f};
      acc2[mi][ni] = (f32x4){0.f, 0.f, 0.f, 0.f};
    }

#pragma unroll
  for (int tt = 0; tt < 2; ++tt) {
    const int k0 = wave * 128 + tt * 64;
    char* wt = reinterpret_cast<char*>(&wbuf[wave][tt & 1][0]);
    // ---- stage this wave's W slice (bf16 only; no barrier needed) ----
#pragma unroll
    for (int q = 0; q < 4; ++q) {
      const int koct = shb + 2 * q;  // 0..7
      union { unsigned short u[8]; bf16x8 b; } pw;
#pragma unroll
      for (int j = 0; j < 8; ++j) {
        const float v = W[(k0 + koct * 8 + j) * OUT_F + n0 + sn];
        pw.u[j] = bf16_bits(v);
      }
      const int woff = sn * 128 + ((koct ^ (sn & 7)) << 4);
      *reinterpret_cast<bf16x8*>(wt + woff) = pw.b;
    }
    // ---- two K=32 substeps ----
#pragma unroll
    for (int sub = 0; sub < 2; ++sub) {
      const int kk = k0 + sub * 32 + h * 8;   // this lane's 8-k base
      const int c = kk >> 3;                  // s_lds chunk index
      // A-frags in registers: xs = bf16(x*s), ss = bf16(s*s); mi = 0,1
      union { unsigned short u[8]; bf16x8 b; } fxs0, fss0, fxs1, fss1;
      {
        const int r0 = lm;
        const float* xp0 = tensor + (m0 + r0) * IN_F + kk;
        float4 xa0 = *reinterpret_cast<const float4*>(xp0);
        float4 xb0 = *reinterpret_cast<const float4*>(xp0 + 4);
        bf16x8 s80 = *reinterpret_cast<const bf16x8*>(
            reinterpret_cast<char*>(s_lds) + r0 * 2048 + ((c ^ (r0 & 7)) << 4));
        const float xv0[8] = {xa0.x, xa0.y, xa0.z, xa0.w, xb0.x, xb0.y, xb0.z, xb0.w};
#pragma unroll
        for (int j = 0; j < 8; ++j) {
          const float sf = bf16_f32((unsigned short)s80[j]);
          fxs0.u[j] = bf16_bits(xv0[j] * sf);
          fss0.u[j] = bf16_bits(sf * sf);
        }
        const int r1 = 16 + lm;
        const float* xp1 = tensor + (m0 + r1) * IN_F + kk;
        float4 xa1 = *reinterpret_cast<const float4*>(xp1);
        float4 xb1 = *reinterpret_cast<const float4*>(xp1 + 4);
        bf16x8 s81 = *reinterpret_cast<const bf16x8*>(
            reinterpret_cast<char*>(s_lds) + r1 * 2048 + ((c ^ (r1 & 7)) << 4));
        const float xv1[8] = {xa1.x, xa1.y, xa1.z, xa1.w, xb1.x, xb1.y, xb1.z, xb1.w};
#pragma unroll
        for (int j = 0; j < 8; ++j) {
          const float sf = bf16_f32((unsigned short)s81[j]);
          fxs1.u[j] = bf16_bits(xv1[j] * sf);
          fss1.u[j] = bf16_bits(sf * sf);
        }
      }
      // B-frags: b1 from LDS, b2 = bf16(b1^2) in registers
#pragma unroll
      for (int ni = 0; ni < 2; ++ni) {
        const int br = ni * 16 + lm;
        const int boff = br * 128 + (((sub * 4 + h) ^ (br & 7)) << 4);
        bf16x8 b1 = *reinterpret_cast<const bf16x8*>(wt + boff);
        union { unsigned short u[8]; bf16x8 b; } b2;
#pragma unroll
        for (int j = 0; j < 8; ++j) {
          const float wv = bf16_f32((unsigned short)b1[j]);
          b2.u[j] = bf16_bits(wv * wv);
        }
        acc1[0][ni] = __builtin_amdgcn_mfma_f32_16x16x32_bf16(fxs0.b, b1,   acc1[0][ni], 0, 0, 0);
        acc2[0][ni] = __builtin_amdgcn_mfma_f32_16x16x32_bf16(fss0.b, b2.b, acc2[0][ni], 0, 0, 0);
        acc1[1][ni] = __builtin_amdgcn_mfma_f32_16x16x32_bf16(fxs1.b, b1,   acc1[1][ni], 0, 0, 0);
        acc2[1][ni] = __builtin_amdgcn_mfma_f32_16x16x32_bf16(fss1.b, b2.b, acc2[1][ni], 0, 0, 0);
      }
    }
  }

  // ---- write partials into this wave's wbuf region (wave-private) ----
  {
    float* cb = reinterpret_cast<float*>(&wbuf[wave][0][0]);
#pragma unroll
    for (int mi = 0; mi < 2; ++mi)
#pragma unroll
      for (int ni = 0; ni < 2; ++ni) {
        const int i1 = mi * 2 + ni;
        *reinterpret_cast<f32x4*>(cb + i1 * 256 + lane * 4) = acc1[mi][ni];
        *reinterpret_cast<f32x4*>(cb + (4 + i1) * 256 + lane * 4) = acc2[mi][ni];
      }
  }
  __syncthreads();

  // ---- combine: wave w sums chunk w (w<4: acc1 quadrant w; w>=4: acc2) ----
  {
    f32x4 tsum = {0.f, 0.f, 0.f, 0.f};
#pragma unroll
    for (int v = 0; v < 8; ++v) {
      const float* src = reinterpret_cast<const float*>(&wbuf[v][0][0]);
      tsum += *reinterpret_cast<const f32x4*>(src + wave * 256 + lane * 4);
    }
    if (wave >= 4) {  // acc2 sums -> scratch (s_lds reused)
      *reinterpret_cast<f32x4*>(
          reinterpret_cast<float*>(s_lds) + (wave - 4) * 256 + lane * 4) = tsum;
    }
    __syncthreads();
    if (wave < 4) {
      f32x4 t2 = *reinterpret_cast<const f32x4*>(
          reinterpret_cast<const float*>(s_lds) + wave * 256 + lane * 4);
      const int mi = wave >> 1;
      const int ni = wave & 1;
      const int col = n0 + ni * 16 + lm;
      const float bs = bias[col];
#pragma unroll
      for (int q = 0; q < 4; ++q) {
        const int row = m0 + mi * 16 + h * 4 + q;
        out[row * OUT_F + col] = tsum[q] * __frsqrt_rn(t2[q] + 1e-8f) + bs;
      }
    }
  }
}

// ---------------------------------------------------------------------------
extern "C" void kernel_launch(void* const* d_in, const int* in_sizes, int n_in,
                              void* d_out, int out_size, void* d_ws, size_t ws_size,
                              hipStream_t stream) {
  const float* tensor = (const float*)d_in[0];  // [256][1024]
  const float* z      = (const float*)d_in[1];  // [256][16]
  const float* W      = (const float*)d_in[2];  // [1024][1024]
  const float* bias   = (const float*)d_in[3];  // [1024]
  const float* lt_w   = (const float*)d_in[4];  // [1024][16]
  const float* lt_b   = (const float*)d_in[5];  // [1024]
  float* out = (float*)d_out;

  fused_mod<<<256, 512, 0, stream>>>(tensor, z, lt_w, lt_b, W, bias, out);
}